// Round 9
// baseline (132.589 us; speedup 1.0000x reference)
//
#include <hip/hip_runtime.h>
#include <hip/hip_bf16.h>

typedef unsigned int u32;
typedef __attribute__((ext_vector_type(8))) short bf16x8;    // 8 bf16 = 4 VGPRs (MFMA A/B frag)
typedef __attribute__((ext_vector_type(16))) float f32x16;   // MFMA C/D frag
typedef __attribute__((ext_vector_type(4))) u32 u32x4;

// ---------------------------------------------------------------------------
// PillarFeatureNet fused (round 9: all algebra inside MFMA, DS 23 -> 12/pair)
//
// x[m,u] = qx(W0+W4+W7) + qy(W1+W5+W8) + qz(W2+W6) + qw·W3
//          - mx·W4 - my·W5 - mz·W6 - cxo·W7 - cyo·W8 + shift   (all BN-scaled)
// A cols: k0..3 raw q | k4 ind (masked=1) | k5 bias 1 | k6..10 pillar-uniform
//         [-mx,-my,-mz,-cxo,-cyo]  (uniform cols built locally by EVERY lane
//         from broadcast sums -> no feature exchange needed)
// B rows: k0..3 Weff | k4 -30000 (mask sink) | k5 shift | k6..10 W4'..W8'
// Centroid sums sx,sy,sz per pillar via a 2nd tiny MFMA (B = identity cols)
// + in-lane 16-row add + xor-32 cross-add + 3 lane-broadcast swizzles.
// Masked rows ~ -30000 -> excluded by row-max; reference's "masked row ==
// shift" restored by max(v, npts<32 ? shift : -inf). relu last (zeros from
// anything are harmless under relu).
// ---------------------------------------------------------------------------

#define XOFF (0.08f)            // vx/2 + pc_range[0]
#define YOFF (0.08f - 39.68f)   // vy/2 + pc_range[1]

__device__ __forceinline__ u32 f2bf_bits(float f) {
    union { float f; u32 u; } v; v.f = f;
    u32 u = v.u;
    u += 0x7fffu + ((u >> 16) & 1u);   // RNE
    return u >> 16;
}
__device__ __forceinline__ short bf1(float f) { return (short)f2bf_bits(f); }

// packed bf16 convert: v_cvt_pk_bf16_f32 (1 instr)
__device__ __forceinline__ u32 pk2(float lo, float hi) {
    __hip_bfloat162 h = __float22bfloat162_rn(make_float2(lo, hi));
    union { __hip_bfloat162 h; u32 u; } v; v.h = h;
    return v.u;
}

// 16-way max, max3-fusable linear chain
__device__ __forceinline__ float vmax16(const f32x16 v) {
    float m = fmaxf(fmaxf(v[0], v[1]), v[2]);
    m = fmaxf(fmaxf(m, v[3]), v[4]);
    m = fmaxf(fmaxf(m, v[5]), v[6]);
    m = fmaxf(fmaxf(m, v[7]), v[8]);
    m = fmaxf(fmaxf(m, v[9]), v[10]);
    m = fmaxf(fmaxf(m, v[11]), v[12]);
    m = fmaxf(fmaxf(m, v[13]), v[14]);
    return fmaxf(m, v[15]);
}

// 16-way sum, balanced tree
__device__ __forceinline__ float vsum16(const f32x16 v) {
    const float a = (v[0] + v[1]) + (v[2] + v[3]);
    const float b = (v[4] + v[5]) + (v[6] + v[7]);
    const float c = (v[8] + v[9]) + (v[10] + v[11]);
    const float d = (v[12] + v[13]) + (v[14] + v[15]);
    return (a + b) + (c + d);
}

// broadcast lane 0/1/2 within each 32-lane group (BitMode: and=0, or=n, xor=0)
__device__ __forceinline__ float bc0(float v) {
    return __builtin_bit_cast(float,
        __builtin_amdgcn_ds_swizzle(__builtin_bit_cast(int, v), 0x0000));
}
__device__ __forceinline__ float bc1(float v) {
    return __builtin_bit_cast(float,
        __builtin_amdgcn_ds_swizzle(__builtin_bit_cast(int, v), 0x0020));
}
__device__ __forceinline__ float bc2(float v) {
    return __builtin_bit_cast(float,
        __builtin_amdgcn_ds_swizzle(__builtin_bit_cast(int, v), 0x0040));
}

__global__ __launch_bounds__(256, 4)
void pfn_mfma(const float* __restrict__ features,
              const int* __restrict__ num_points,
              const int* __restrict__ coors,
              const float* __restrict__ W,
              const float* __restrict__ gamma,
              const float* __restrict__ beta,
              const float* __restrict__ rmean,
              const float* __restrict__ rvar,
              float* __restrict__ out,
              int n_total)
{
    const int lane = threadIdx.x & 63;
    const int wid  = threadIdx.x >> 6;
    const int half = lane >> 5;          // 0 = pillar A rows k0..7, 1 = k8..15
    const int m    = lane & 31;          // point row / channel column
    const int waves_total = gridDim.x * 4;
    const int gwave = blockIdx.x * 4 + wid;

    // ---- per-wave setup: BN-fold, composite B rows -----------------------
    const int c0 = m, c1 = 32 + m;       // tile0 ch 0..31, tile1 ch 32..63
    const float inv0   = gamma[c0] / sqrtf(rvar[c0] + 1e-3f);
    const float shift0 = beta[c0] - rmean[c0] * inv0;
    float inv1 = 0.0f, shift1 = 0.0f;
    if (c1 < 63) {
        inv1   = gamma[c1] / sqrtf(rvar[c1] + 1e-3f);
        shift1 = beta[c1] - rmean[c1] * inv1;
    }
    const float shift_me = half ? shift1 : shift0;

    float wp0[9], wp1[9];
#pragma unroll
    for (int c = 0; c < 9; ++c) {
        wp0[c] = W[c0 * 9 + c] * inv0;
        wp1[c] = (c1 < 63) ? W[c1 * 9 + c] * inv1 : 0.0f;
    }
    // row-value map for the composite B matrix
    auto rowv = [](int k, const float* wp, float sh) -> float {
        switch (k) {
            case 0:  return wp[0] + wp[4] + wp[7];
            case 1:  return wp[1] + wp[5] + wp[8];
            case 2:  return wp[2] + wp[6];
            case 3:  return wp[3];
            case 4:  return -30000.0f;     // mask sink (× ind)
            case 5:  return sh;            // bias (× 1)
            case 6:  return wp[4];         // × -mx
            case 7:  return wp[5];         // × -my
            case 8:  return wp[6];         // × -mz
            case 9:  return wp[7];         // × -cxo
            case 10: return wp[8];         // × -cyo
            default: return 0.0f;
        }
    };
    bf16x8 b0, b1, bs;
#pragma unroll
    for (int j = 0; j < 8; ++j) {
        const int k = half * 8 + j;
        b0[j] = bf1(rowv(k, wp0, shift0));
        b1[j] = bf1(rowv(k, wp1, shift1));
        // identity columns e_x,e_y,e_z for the sum-MFMA: B[k][n]=1 iff k==n<3
        bs[j] = (half == 0 && j == m && m < 3) ? bf1(1.0f) : (short)0;
    }

    const f32x16 zacc = {};
    const float4* featv = reinterpret_cast<const float4*>(features);
    const int n_pairs = (n_total + 1) >> 1;
    const int iters   = (n_pairs + waves_total - 1) / waves_total;

    struct PairIn { float4 q; int npA, npB; int2 ccA, ccB; };
    auto load_pair = [&](int pr) -> PairIn {
        PairIn r;
        const int base = min(pr, n_pairs - 1) * 2;
        const int iB   = min(base + 1, n_total - 1);
        const int nh   = min(base + half, n_total - 1);
        r.npA = num_points[base];
        r.npB = num_points[iB];
        r.ccA = *reinterpret_cast<const int2*>(coors + base * 4 + 2);  // [y,x]
        r.ccB = *reinterpret_cast<const int2*>(coors + iB * 4 + 2);
        r.q   = featv[nh * 32 + m];
        return r;
    };

    int pa = gwave;
    PairIn cur = load_pair(pa);

    for (int it = 0; it < iters; ++it) {
        PairIn nx = load_pair(pa + waves_total);   // prefetch next

        // ---- raw point packs + single 2-dword cross-half q exchange -------
        const float4 q = cur.q;
        const u32 p0 = pk2(q.x, q.y);
        const u32 p1 = pk2(q.z, q.w);
        const u32 x0 = __shfl_xor(p0, 32);         // pillar B's q for lanes<32
        const u32 x1 = __shfl_xor(p1, 32);

        // ---- centroid sums via sum-MFMA (identity B cols) -----------------
        u32x4 sa4 = {half ? 0u : p0, half ? 0u : p1, 0u, 0u};
        u32x4 sb4 = {half ? 0u : x0, half ? 0u : x1, 0u, 0u};
        const f32x16 sA = __builtin_amdgcn_mfma_f32_32x32x16_bf16(
            __builtin_bit_cast(bf16x8, sa4), bs, zacc, 0, 0, 0);
        const f32x16 sB = __builtin_amdgcn_mfma_f32_32x32x16_bf16(
            __builtin_bit_cast(bf16x8, sb4), bs, zacc, 0, 0, 0);
        float tA = vsum16(sA); tA += __shfl_xor(tA, 32);   // full 32-row sums
        float tB = vsum16(sB); tB += __shfl_xor(tB, 32);
        const float sxA = bc0(tA), syA = bc1(tA), szA = bc2(tA);
        const float sxB = bc0(tB), syB = bc1(tB), szB = bc2(tB);

        // ---- pillar-uniform A columns, built locally by every lane --------
        const float rnpA = __builtin_amdgcn_rcpf((float)cur.npA);
        const float rnpB = __builtin_amdgcn_rcpf((float)cur.npB);
        const float cxoA = (float)cur.ccA.y * 0.16f + XOFF;
        const float cyoA = (float)cur.ccA.x * 0.16f + YOFF;
        const float cxoB = (float)cur.ccB.y * 0.16f + XOFF;
        const float cyoB = (float)cur.ccB.x * 0.16f + YOFF;
        const u32 d2A = pk2((m < cur.npA) ? 0.0f : 1.0f, 1.0f);  // [ind, bias]
        const u32 d2B = pk2((m < cur.npB) ? 0.0f : 1.0f, 1.0f);
        const u32 d3A = pk2(-sxA * rnpA, -syA * rnpA);           // [-mx, -my]
        const u32 d3B = pk2(-sxB * rnpB, -syB * rnpB);
        const u32 d4A = pk2(-szA * rnpA, -cxoA);                 // [-mz, -cxo]
        const u32 d4B = pk2(-szB * rnpB, -cxoB);
        const u32 d5A = pk2(-cyoA, 0.0f);                        // [-cyo, 0]
        const u32 d5B = pk2(-cyoB, 0.0f);

        // A frags: lanes<32 k0..7 = [q, q, (ind,1), (-mx,-my)];
        //          lanes>=32 k8..15 = [(-mz,-cxo), (-cyo,0), 0, 0]
        u32x4 aa = {half ? d4A : p0, half ? d5A : p1,
                    half ? 0u : d2A, half ? 0u : d3A};
        u32x4 ab = {half ? d4B : x0, half ? d5B : x1,
                    half ? 0u : d2B, half ? 0u : d3B};
        const bf16x8 aA = __builtin_bit_cast(bf16x8, aa);
        const bf16x8 aB = __builtin_bit_cast(bf16x8, ab);

        // ---- main MFMAs + pooled max --------------------------------------
        const f32x16 cA0 = __builtin_amdgcn_mfma_f32_32x32x16_bf16(aA, b0, zacc, 0, 0, 0);
        const f32x16 cA1 = __builtin_amdgcn_mfma_f32_32x32x16_bf16(aA, b1, zacc, 0, 0, 0);
        const float tA0 = vmax16(cA0);
        const float tA1 = vmax16(cA1);
        const f32x16 cB0 = __builtin_amdgcn_mfma_f32_32x32x16_bf16(aB, b0, zacc, 0, 0, 0);
        const f32x16 cB1 = __builtin_amdgcn_mfma_f32_32x32x16_bf16(aB, b1, zacc, 0, 0, 0);
        const float tB0 = vmax16(cB0);
        const float tB1 = vmax16(cB1);

        // pre-select tile merge: 1 exchange per pillar
        const float keepA = half ? tA1 : tA0, sendA = half ? tA0 : tA1;
        const float keepB = half ? tB1 : tB0, sendB = half ? tB0 : tB1;
        float vA = fmaxf(keepA, __shfl_xor(sendA, 32));
        float vB = fmaxf(keepB, __shfl_xor(sendB, 32));

        // masked-row value == shift (only when a masked row exists), then relu
        if (cur.npA < 32) vA = fmaxf(vA, shift_me);
        if (cur.npB < 32) vB = fmaxf(vB, shift_me);
        vA = fmaxf(vA, 0.0f);
        vB = fmaxf(vB, 0.0f);

        // channel 63 = num_points (both counts loaded locally; no exchange)
        if (lane == 63) { vA = (float)cur.npA; vB = (float)cur.npB; }

        if (pa < n_pairs) {
            const int nA = pa * 2;
            out[nA * 64 + lane] = vA;
            if (nA + 1 < n_total) out[(nA + 1) * 64 + lane] = vB;
        }

        pa += waves_total;
        cur = nx;
    }
}

extern "C" void kernel_launch(void* const* d_in, const int* in_sizes, int n_in,
                              void* d_out, int out_size, void* d_ws, size_t ws_size,
                              hipStream_t stream) {
    const float* features   = (const float*)d_in[0];
    const int*   num_points = (const int*)d_in[1];
    const int*   coors      = (const int*)d_in[2];
    const float* W          = (const float*)d_in[3];
    const float* gamma      = (const float*)d_in[4];
    const float* beta       = (const float*)d_in[5];
    const float* rmean      = (const float*)d_in[6];
    const float* rvar       = (const float*)d_in[7];
    float* out              = (float*)d_out;

    const int n_total = in_sizes[1];   // N pillars

    // 2048 blocks x 4 waves = 8192 waves (R6-verified traffic-clean);
    // 1 pillar-pair per iteration, ~7.3 iterations per wave.
    const int blocks = 2048;
    pfn_mfma<<<blocks, 256, 0, stream>>>(features, num_points, coors, W,
                                         gamma, beta, rmean, rvar, out, n_total);
}